// Round 3
// baseline (146.447 us; speedup 1.0000x reference)
//
#include <hip/hip_runtime.h>
#include <math.h>

#define HH 2048
#define WW 2048
#define HWP (HH*WW)          // plane stride (elements)
#define NBLK 64              // 8x8 blocks per workgroup (one 512x8 strip)
#define LSTRIDE 68           // 68*4=272B slot stride: 16B-aligned, b128 conflict-free

// ---- f64 truth for 0.5*cos(pi*m/16); f32 casts == np.float32(A) exactly ----
#define C1d 0.49039264020161522
#define C2d 0.46193976625564337
#define C3d 0.41573480615127262
#define C4d 0.35355339059327379
#define C5d 0.27778511650980111
#define C6d 0.19134171618254489
#define C7d 0.097545161008064134
#define F(x) ((float)(x))

static constexpr float AFc[8][8] = {
 { F(C4d), F(C4d), F(C4d), F(C4d), F(C4d), F(C4d), F(C4d), F(C4d)},
 { F(C1d), F(C3d), F(C5d), F(C7d),-F(C7d),-F(C5d),-F(C3d),-F(C1d)},
 { F(C2d), F(C6d),-F(C6d),-F(C2d),-F(C2d),-F(C6d), F(C6d), F(C2d)},
 { F(C3d),-F(C7d),-F(C1d),-F(C5d), F(C5d), F(C1d), F(C7d),-F(C3d)},
 { F(C4d),-F(C4d),-F(C4d), F(C4d), F(C4d),-F(C4d),-F(C4d), F(C4d)},
 { F(C5d),-F(C1d), F(C7d), F(C3d),-F(C3d),-F(C7d), F(C1d),-F(C5d)},
 { F(C6d),-F(C2d), F(C2d),-F(C6d),-F(C6d), F(C2d),-F(C2d), F(C6d)},
 { F(C7d),-F(C5d), F(C3d),-F(C1d), F(C1d),-F(C3d), F(C5d),-F(C7d)}
};

__device__ __constant__ float g_AF[64] = {
  F(C4d), F(C4d), F(C4d), F(C4d), F(C4d), F(C4d), F(C4d), F(C4d),
  F(C1d), F(C3d), F(C5d), F(C7d),-F(C7d),-F(C5d),-F(C3d),-F(C1d),
  F(C2d), F(C6d),-F(C6d),-F(C2d),-F(C2d),-F(C6d), F(C6d), F(C2d),
  F(C3d),-F(C7d),-F(C1d),-F(C5d), F(C5d), F(C1d), F(C7d),-F(C3d),
  F(C4d),-F(C4d),-F(C4d), F(C4d), F(C4d),-F(C4d),-F(C4d), F(C4d),
  F(C5d),-F(C1d), F(C7d), F(C3d),-F(C3d),-F(C7d), F(C1d),-F(C5d),
  F(C6d),-F(C2d), F(C2d),-F(C6d),-F(C6d), F(C2d),-F(C2d), F(C6d),
  F(C7d),-F(C5d), F(C3d),-F(C1d), F(C1d),-F(C3d), F(C5d),-F(C7d)
};

// Quant tables as f32 (Q50 -> s=1.0 exactly; integers exact in f32)
__device__ __constant__ float g_Q[128] = {
 // luma
 16,11,10,16,24,40,51,61,  12,12,14,19,26,58,60,55,
 14,13,16,24,40,57,69,56,  14,17,22,29,51,87,80,62,
 18,22,37,56,68,109,103,77, 24,35,55,64,81,104,113,92,
 49,64,78,87,103,121,120,101, 72,92,95,98,112,100,103,99,
 // chroma
 17,18,24,47,99,99,99,99,  18,21,26,66,99,99,99,99,
 24,26,56,99,99,99,99,99,  47,66,99,99,99,99,99,99,
 99,99,99,99,99,99,99,99,  99,99,99,99,99,99,99,99,
 99,99,99,99,99,99,99,99,  99,99,99,99,99,99,99,99};

// ---- color constants: np's _w is float32; inverse from the f32-rounded w ----
static constexpr double W00=(double)0.299f,     W01=(double)0.587f,     W02=(double)0.114f;
static constexpr double W10=(double)-0.168736f, W11=(double)-0.331264f, W12=(double)0.5f;
static constexpr double W20=(double)0.5f,       W21=(double)-0.418688f, W22=(double)-0.081312f;
static constexpr double DETW = W00*(W11*W22 - W12*W21) - W01*(W10*W22 - W12*W20)
                             + W02*(W10*W21 - W11*W20);
static constexpr double I00=(W11*W22-W12*W21)/DETW, I01=(W02*W21-W01*W22)/DETW, I02=(W01*W12-W02*W11)/DETW;
static constexpr double I10=(W12*W20-W10*W22)/DETW, I11=(W00*W22-W02*W20)/DETW, I12=(W02*W10-W00*W12)/DETW;
static constexpr double I20=(W10*W21-W11*W20)/DETW, I21=(W01*W20-W00*W21)/DETW, I22=(W00*W11-W01*W10)/DETW;
// mean/std as np computes them: f32(125.3f/255f) etc.; fold /255,-mean,/std
static constexpr float  m0f = 125.3f/255.0f, m1f = 123.0f/255.0f, m2f = 113.9f/255.0f;
static constexpr float  s0f = 63.0f/255.0f,  s1f = 62.1f/255.0f,  s2f = 66.7f/255.0f;
static constexpr double M0d = 255.0*(double)m0f, M1d = 255.0*(double)m1f, M2d = 255.0*(double)m2f;
static constexpr double iS0d = 1.0/(255.0*(double)s0f), iS1d = 1.0/(255.0*(double)s1f), iS2d = 1.0/(255.0*(double)s2f);

__global__ void __launch_bounds__(192, 2)
jpeg_kernel(const float* __restrict__ in, float* __restrict__ out) {
#pragma clang fp contract(off)   // pre-round path must not fuse mul+add
  __shared__ float lds[3 * NBLK * LSTRIDE];   // 52224 B
  __shared__ float Alds[64];
  __shared__ float Qlds[128];

  const int tid  = threadIdx.x;
  const int gid  = blockIdx.x;        // 0..1023
  const int brow = gid >> 2;          // block-row 0..255
  const int strip = gid & 3;
  const int rowbase = brow * 8;
  const int colbase = strip * 512;
  const int c   = tid >> 6;           // channel 0..2 (wave-uniform)
  const int blk = tid & 63;           // 8x8 block within strip

  if (tid < 64)        Alds[tid] = g_AF[tid];
  else if (tid < 192)  Qlds[tid - 64] = g_Q[tid - 64];
  __syncthreads();

  const float* pR = in;
  const float* pG = in + HWP;
  const float* pB = in + 2 * HWP;
  const size_t base = (size_t)rowbase * WW + colbase + blk * 8;

  // per-wave forward color row (f32, as np's _w)
  float wc0, wc1, wc2, bc;
  if (c == 0)      { wc0 = 0.299f;     wc1 = 0.587f;     wc2 = 0.114f;     bc = 0.0f;   }
  else if (c == 1) { wc0 = -0.168736f; wc1 = -0.331264f; wc2 = 0.5f;       bc = 128.0f; }
  else             { wc0 = 0.5f;       wc1 = -0.418688f; wc2 = -0.081312f; bc = 128.0f; }

  // ---- Phase A: RGB -> YUV channel c, f32, sgemm-style fma chain + bias add
  float X[64];
  #pragma unroll
  for (int r = 0; r < 8; ++r) {
    const float* rowR = pR + base + (size_t)r * WW;
    const float* rowG = pG + base + (size_t)r * WW;
    const float* rowB = pB + base + (size_t)r * WW;
    float4 R0 = *(const float4*)rowR, R1 = *(const float4*)(rowR + 4);
    float4 G0 = *(const float4*)rowG, G1 = *(const float4*)(rowG + 4);
    float4 B0 = *(const float4*)rowB, B1 = *(const float4*)(rowB + 4);
    float fr[8] = {R0.x,R0.y,R0.z,R0.w,R1.x,R1.y,R1.z,R1.w};
    float fg[8] = {G0.x,G0.y,G0.z,G0.w,G1.x,G1.y,G1.z,G1.w};
    float fb[8] = {B0.x,B0.y,B0.z,B0.w,B1.x,B1.y,B1.z,B1.w};
    #pragma unroll
    for (int p = 0; p < 8; ++p) {
      float acc = fmaf(wc2, fb[p], fmaf(wc1, fg[p], wc0 * fr[p]));  // sgemm k-ascend
      X[r*8+p] = acc + bc;                                          // separate +b op
    }
  }

  // ---- Phase B: np.einsum-order SOP DCT (j outer, k inner, (A*X)*A terms),
  //      IEEE f32 divide by Q, round half-even, soft-quant; U -> own LDS slot.
  float* slot = lds + (c * NBLK + blk) * LSTRIDE;
  const float* Qrow = Qlds + ((c == 0) ? 0 : 64);
  for (int i = 0; i < 8; ++i) {                       // runtime loop (code size)
    float accs[8] = {0.f,0.f,0.f,0.f,0.f,0.f,0.f,0.f};
    #pragma unroll
    for (int j = 0; j < 8; ++j) {
      const float aij = Alds[i*8 + j];                // lane-uniform LDS broadcast
      float P[8];
      #pragma unroll
      for (int k = 0; k < 8; ++k) P[k] = aij * X[j*8 + k];   // fl(A[i,j]*X[j,k])
      #pragma unroll
      for (int l = 0; l < 8; ++l) {
        #pragma unroll
        for (int k = 0; k < 8; ++k)
          accs[l] = accs[l] + P[k] * AFc[l][k];       // fl(fl(P)*A[l,k]), seq add
      }
    }
    #pragma unroll
    for (int l = 0; l < 8; ++l) {
      const float q  = Qrow[i*8 + l];
      const float v  = accs[l] / q;                   // IEEE f32 divide
      const float rr = rintf(v);                      // half-to-even == np.round
      const float e  = v - rr;
      const float e3 = (e * e) * e;
      const float qd = rr + e3;
      slot[i*8 + l] = qd * q;
    }
  }

  // ---- Phase B2: factorized f32 IDCT (post-round: smooth, order-insensitive)
  float U[64];
  #pragma unroll
  for (int t4 = 0; t4 < 16; ++t4)
    *(float4*)(U + 4*t4) = *(const float4*)(slot + 4*t4);
  // row pass: V[j][n] = sum_k U[j][k] * A[k][n]
  #pragma unroll
  for (int j = 0; j < 8; ++j) {
    float t[8];
    #pragma unroll
    for (int n = 0; n < 8; ++n) {
      float acc = U[j*8+0] * AFc[0][n];
      #pragma unroll
      for (int k = 1; k < 8; ++k) acc = fmaf(U[j*8+k], AFc[k][n], acc);
      t[n] = acc;
    }
    #pragma unroll
    for (int n = 0; n < 8; ++n) U[j*8+n] = t[n];
  }
  // col pass: rec[m][n] = sum_j A[j][m] * V[j][n]
  #pragma unroll
  for (int n = 0; n < 8; ++n) {
    float t[8];
    #pragma unroll
    for (int m = 0; m < 8; ++m) {
      float acc = AFc[0][m] * U[0*8+n];
      #pragma unroll
      for (int j = 1; j < 8; ++j) acc = fmaf(AFc[j][m], U[j*8+n], acc);
      t[m] = acc;
    }
    #pragma unroll
    for (int m = 0; m < 8; ++m) U[m*8+n] = t[m];
  }
  #pragma unroll
  for (int t4 = 0; t4 < 16; ++t4)
    *(float4*)(slot + 4*t4) = *(const float4*)(U + 4*t4);
  __syncthreads();

  // ---- Phase D: YUV->RGB->normalize, coalesced float4 stores
  const float i00=F(I00), i01=F(I01), i02=F(I02);
  const float i10=F(I10), i11=F(I11), i12=F(I12);
  const float i20=F(I20), i21=F(I21), i22=F(I22);
  const float M0=F(M0d), M1=F(M1d), M2=F(M2d);
  const float iS0=F(iS0d), iS1=F(iS1d), iS2=F(iS2d);
  for (int q = tid; q < 1024; q += 192) {
    const int r    = q >> 7;
    const int col4 = q & 127;
    const int b2   = col4 >> 1;
    const int wi   = (r << 3) + ((col4 & 1) << 2);
    const float4 Yy = *(const float4*)(lds + (0*NBLK + b2)*LSTRIDE + wi);
    const float4 Uu = *(const float4*)(lds + (1*NBLK + b2)*LSTRIDE + wi);
    const float4 Vv = *(const float4*)(lds + (2*NBLK + b2)*LSTRIDE + wi);
    const size_t off = (size_t)(rowbase + r) * WW + (colbase + (col4 << 2));
    float4 o0, o1, o2;
#define MIXC(cm) { \
    const float uu = Uu.cm - 128.0f, vv = Vv.cm - 128.0f, yy = Yy.cm; \
    o0.cm = (fmaf(i02, vv, fmaf(i01, uu, i00*yy)) - M0) * iS0; \
    o1.cm = (fmaf(i12, vv, fmaf(i11, uu, i10*yy)) - M1) * iS1; \
    o2.cm = (fmaf(i22, vv, fmaf(i21, uu, i20*yy)) - M2) * iS2; }
    MIXC(x) MIXC(y) MIXC(z) MIXC(w)
#undef MIXC
    *(float4*)(out + off)          = o0;
    *(float4*)(out + HWP + off)    = o1;
    *(float4*)(out + 2*HWP + off)  = o2;
  }
}

extern "C" void kernel_launch(void* const* d_in, const int* in_sizes, int n_in,
                              void* d_out, int out_size, void* d_ws, size_t ws_size,
                              hipStream_t stream) {
  const float* in = (const float*)d_in[0];
  float* out = (float*)d_out;
  dim3 grid((HH/8) * (WW/512));   // 1024 workgroups
  dim3 block(192);                // 3 waves: one per channel, 64 blocks each
  jpeg_kernel<<<grid, block, 0, stream>>>(in, out);
}

// Round 4
// 130.164 us; speedup vs baseline: 1.1251x; 1.1251x over previous
//
#include <hip/hip_runtime.h>
#include <math.h>

#define HH 2048
#define WW 2048
#define HWP (HH*WW)          // plane stride (elements)
#define NBLK 64              // 8x8 blocks per workgroup (one 512x8 strip)
#define SLOTH 72             // halves per (c,blk) slot; 144B stride == canonical float4 bank pattern (4i mod 32) -> conflict-free b128

typedef _Float16 h8 __attribute__((ext_vector_type(8)));   // 16B LDS vector

// ---- f64 truth for 0.5*cos(pi*m/16); f32 casts == np.float32(A) exactly ----
#define C1d 0.49039264020161522
#define C2d 0.46193976625564337
#define C3d 0.41573480615127262
#define C4d 0.35355339059327379
#define C5d 0.27778511650980111
#define C6d 0.19134171618254489
#define C7d 0.097545161008064134
#define F(x) ((float)(x))

static constexpr float AFc[8][8] = {
 { F(C4d), F(C4d), F(C4d), F(C4d), F(C4d), F(C4d), F(C4d), F(C4d)},
 { F(C1d), F(C3d), F(C5d), F(C7d),-F(C7d),-F(C5d),-F(C3d),-F(C1d)},
 { F(C2d), F(C6d),-F(C6d),-F(C2d),-F(C2d),-F(C6d), F(C6d), F(C2d)},
 { F(C3d),-F(C7d),-F(C1d),-F(C5d), F(C5d), F(C1d), F(C7d),-F(C3d)},
 { F(C4d),-F(C4d),-F(C4d), F(C4d), F(C4d),-F(C4d),-F(C4d), F(C4d)},
 { F(C5d),-F(C1d), F(C7d), F(C3d),-F(C3d),-F(C7d), F(C1d),-F(C5d)},
 { F(C6d),-F(C2d), F(C2d),-F(C6d),-F(C6d), F(C2d),-F(C2d), F(C6d)},
 { F(C7d),-F(C5d), F(C3d),-F(C1d), F(C1d),-F(C3d), F(C5d),-F(C7d)}
};

__device__ __constant__ float g_AF[64] = {
  F(C4d), F(C4d), F(C4d), F(C4d), F(C4d), F(C4d), F(C4d), F(C4d),
  F(C1d), F(C3d), F(C5d), F(C7d),-F(C7d),-F(C5d),-F(C3d),-F(C1d),
  F(C2d), F(C6d),-F(C6d),-F(C2d),-F(C2d),-F(C6d), F(C6d), F(C2d),
  F(C3d),-F(C7d),-F(C1d),-F(C5d), F(C5d), F(C1d), F(C7d),-F(C3d),
  F(C4d),-F(C4d),-F(C4d), F(C4d), F(C4d),-F(C4d),-F(C4d), F(C4d),
  F(C5d),-F(C1d), F(C7d), F(C3d),-F(C3d),-F(C7d), F(C1d),-F(C5d),
  F(C6d),-F(C2d), F(C2d),-F(C6d),-F(C6d), F(C2d),-F(C2d), F(C6d),
  F(C7d),-F(C5d), F(C3d),-F(C1d), F(C1d),-F(C3d), F(C5d),-F(C7d)
};

// Quant tables as f32 (Q50 -> s=1.0 exactly; integers exact in f32)
__device__ __constant__ float g_Q[128] = {
 16,11,10,16,24,40,51,61,  12,12,14,19,26,58,60,55,
 14,13,16,24,40,57,69,56,  14,17,22,29,51,87,80,62,
 18,22,37,56,68,109,103,77, 24,35,55,64,81,104,113,92,
 49,64,78,87,103,121,120,101, 72,92,95,98,112,100,103,99,
 17,18,24,47,99,99,99,99,  18,21,26,66,99,99,99,99,
 24,26,56,99,99,99,99,99,  47,66,99,99,99,99,99,99,
 99,99,99,99,99,99,99,99,  99,99,99,99,99,99,99,99,
 99,99,99,99,99,99,99,99,  99,99,99,99,99,99,99,99};

// ---- color constants: np's _w is float32; inverse from the f32-rounded w ----
static constexpr double W00=(double)0.299f,     W01=(double)0.587f,     W02=(double)0.114f;
static constexpr double W10=(double)-0.168736f, W11=(double)-0.331264f, W12=(double)0.5f;
static constexpr double W20=(double)0.5f,       W21=(double)-0.418688f, W22=(double)-0.081312f;
static constexpr double DETW = W00*(W11*W22 - W12*W21) - W01*(W10*W22 - W12*W20)
                             + W02*(W10*W21 - W11*W20);
static constexpr double I00=(W11*W22-W12*W21)/DETW, I01=(W02*W21-W01*W22)/DETW, I02=(W01*W12-W02*W11)/DETW;
static constexpr double I10=(W12*W20-W10*W22)/DETW, I11=(W00*W22-W02*W20)/DETW, I12=(W02*W10-W00*W12)/DETW;
static constexpr double I20=(W10*W21-W11*W20)/DETW, I21=(W01*W20-W00*W21)/DETW, I22=(W00*W11-W01*W10)/DETW;
static constexpr float  m0f = 125.3f/255.0f, m1f = 123.0f/255.0f, m2f = 113.9f/255.0f;
static constexpr float  s0f = 63.0f/255.0f,  s1f = 62.1f/255.0f,  s2f = 66.7f/255.0f;
static constexpr double M0d = 255.0*(double)m0f, M1d = 255.0*(double)m1f, M2d = 255.0*(double)m2f;
static constexpr double iS0d = 1.0/(255.0*(double)s0f), iS1d = 1.0/(255.0*(double)s1f), iS2d = 1.0/(255.0*(double)s2f);

__global__ void __launch_bounds__(192, 3)
jpeg_kernel(const float* __restrict__ in, float* __restrict__ out) {
#pragma clang fp contract(off)   // pre-round path must not fuse mul+add
  __shared__ _Float16 recs[3 * NBLK * SLOTH];   // 27648 B -> 4 WG/CU (grid-limited)
  __shared__ float Alds[64];
  __shared__ float Qlds[128];

  const int tid  = threadIdx.x;
  const int gid  = blockIdx.x;        // 0..1023
  const int brow = gid >> 2;          // block-row 0..255
  const int strip = gid & 3;
  const int rowbase = brow * 8;
  const int colbase = strip * 512;
  const int c   = tid >> 6;           // channel 0..2 (wave-uniform)
  const int blk = tid & 63;           // 8x8 block within strip

  if (tid < 64)        Alds[tid] = g_AF[tid];
  else if (tid < 192)  Qlds[tid - 64] = g_Q[tid - 64];
  __syncthreads();

  const float* pR = in;
  const float* pG = in + HWP;
  const float* pB = in + 2 * HWP;
  const size_t base = (size_t)rowbase * WW + colbase + blk * 8;

  // per-wave forward color row (f32, as np's _w)
  float wc0, wc1, wc2, bc;
  if (c == 0)      { wc0 = 0.299f;     wc1 = 0.587f;     wc2 = 0.114f;     bc = 0.0f;   }
  else if (c == 1) { wc0 = -0.168736f; wc1 = -0.331264f; wc2 = 0.5f;       bc = 128.0f; }
  else             { wc0 = 0.5f;       wc1 = -0.418688f; wc2 = -0.081312f; bc = 128.0f; }

  // ---- Phase A: RGB -> YUV channel c, f32, sgemm-style fma chain + bias add
  // (bit-identical to the R3 passing kernel — do not reorder)
  float X[64];
  #pragma unroll
  for (int r = 0; r < 8; ++r) {
    const float* rowR = pR + base + (size_t)r * WW;
    const float* rowG = pG + base + (size_t)r * WW;
    const float* rowB = pB + base + (size_t)r * WW;
    float4 R0 = *(const float4*)rowR, R1 = *(const float4*)(rowR + 4);
    float4 G0 = *(const float4*)rowG, G1 = *(const float4*)(rowG + 4);
    float4 B0 = *(const float4*)rowB, B1 = *(const float4*)(rowB + 4);
    float fr[8] = {R0.x,R0.y,R0.z,R0.w,R1.x,R1.y,R1.z,R1.w};
    float fg[8] = {G0.x,G0.y,G0.z,G0.w,G1.x,G1.y,G1.z,G1.w};
    float fb[8] = {B0.x,B0.y,B0.z,B0.w,B1.x,B1.y,B1.z,B1.w};
    #pragma unroll
    for (int p = 0; p < 8; ++p) {
      float acc = fmaf(wc2, fb[p], fmaf(wc1, fg[p], wc0 * fr[p]));
      X[r*8+p] = acc + bc;
    }
  }

  // ---- Phase B: np.einsum-order SOP DCT (bit-identical order to R3),
  //      quant/round in f32 registers; U row -> one ds_write_b128 (f16).
  _Float16* slot = recs + (c * NBLK + blk) * SLOTH;
  const float* Qrow = Qlds + ((c == 0) ? 0 : 64);
  for (int i = 0; i < 8; ++i) {                       // runtime loop (icache)
    float accs[8] = {0.f,0.f,0.f,0.f,0.f,0.f,0.f,0.f};
    #pragma unroll
    for (int j = 0; j < 8; ++j) {
      const float aij = Alds[i*8 + j];                // lane-uniform broadcast
      float P[8];
      #pragma unroll
      for (int k = 0; k < 8; ++k) P[k] = aij * X[j*8 + k];   // fl(A[i,j]*X[j,k])
      #pragma unroll
      for (int l = 0; l < 8; ++l) {
        #pragma unroll
        for (int k = 0; k < 8; ++k)
          accs[l] = accs[l] + P[k] * AFc[l][k];       // fl(fl(P)*A[l,k]), seq add
      }
    }
    h8 rowv;
    #pragma unroll
    for (int l = 0; l < 8; ++l) {
      const float q  = Qrow[i*8 + l];
      const float v  = accs[l] / q;                   // IEEE f32 divide
      const float rr = rintf(v);                      // half-to-even == np.round
      const float e  = v - rr;
      const float qd = rr + (e * e) * e;
      rowv[l] = (_Float16)(qd * q);                   // post-round: f16 is safe
    }
    *(h8*)(slot + i*8) = rowv;                        // 16B, conflict-free
  }

  // ---- Phase B2: factorized f32 IDCT (post-round smooth); f16 in/out of LDS
  float U[64];
  #pragma unroll
  for (int rw = 0; rw < 8; ++rw) {
    h8 v = *(const h8*)(slot + rw*8);
    #pragma unroll
    for (int k = 0; k < 8; ++k) U[rw*8+k] = (float)v[k];
  }
  #pragma unroll
  for (int j = 0; j < 8; ++j) {        // row pass: V[j][n] = sum_k U[j][k]*A[k][n]
    float t[8];
    #pragma unroll
    for (int n = 0; n < 8; ++n) {
      float acc = U[j*8+0] * AFc[0][n];
      #pragma unroll
      for (int k = 1; k < 8; ++k) acc = fmaf(U[j*8+k], AFc[k][n], acc);
      t[n] = acc;
    }
    #pragma unroll
    for (int n = 0; n < 8; ++n) U[j*8+n] = t[n];
  }
  #pragma unroll
  for (int n = 0; n < 8; ++n) {        // col pass: rec[m][n] = sum_j A[j][m]*V[j][n]
    float t[8];
    #pragma unroll
    for (int m = 0; m < 8; ++m) {
      float acc = AFc[0][m] * U[0*8+n];
      #pragma unroll
      for (int j = 1; j < 8; ++j) acc = fmaf(AFc[j][m], U[j*8+n], acc);
      t[m] = acc;
    }
    #pragma unroll
    for (int m = 0; m < 8; ++m) U[m*8+n] = t[m];
  }
  #pragma unroll
  for (int rw = 0; rw < 8; ++rw) {
    h8 v;
    #pragma unroll
    for (int k = 0; k < 8; ++k) v[k] = (_Float16)U[rw*8+k];
    *(h8*)(slot + rw*8) = v;
  }
  __syncthreads();

  // ---- Phase D: YUV->RGB->normalize; 8 pixels/group, coalesced stores
  const float i00=F(I00), i01=F(I01), i02=F(I02);
  const float i10=F(I10), i11=F(I11), i12=F(I12);
  const float i20=F(I20), i21=F(I21), i22=F(I22);
  const float M0=F(M0d), M1=F(M1d), M2=F(M2d);
  const float iS0=F(iS0d), iS1=F(iS1d), iS2=F(iS2d);
  for (int g = tid; g < 512; g += 192) {
    const int b = g & 63;
    const int r = g >> 6;
    const h8 Yv = *(const h8*)(recs + (0*NBLK + b)*SLOTH + r*8);
    const h8 Uv = *(const h8*)(recs + (1*NBLK + b)*SLOTH + r*8);
    const h8 Vv = *(const h8*)(recs + (2*NBLK + b)*SLOTH + r*8);
    float o0[8], o1[8], o2[8];
    #pragma unroll
    for (int p = 0; p < 8; ++p) {
      const float yy = (float)Yv[p];
      const float uu = (float)Uv[p] - 128.0f;
      const float vv = (float)Vv[p] - 128.0f;
      o0[p] = (fmaf(i02, vv, fmaf(i01, uu, i00*yy)) - M0) * iS0;
      o1[p] = (fmaf(i12, vv, fmaf(i11, uu, i10*yy)) - M1) * iS1;
      o2[p] = (fmaf(i22, vv, fmaf(i21, uu, i20*yy)) - M2) * iS2;
    }
    const size_t off = (size_t)(rowbase + r) * WW + colbase + b * 8;
    *(float4*)(out + off)             = make_float4(o0[0],o0[1],o0[2],o0[3]);
    *(float4*)(out + off + 4)         = make_float4(o0[4],o0[5],o0[6],o0[7]);
    *(float4*)(out + HWP + off)       = make_float4(o1[0],o1[1],o1[2],o1[3]);
    *(float4*)(out + HWP + off + 4)   = make_float4(o1[4],o1[5],o1[6],o1[7]);
    *(float4*)(out + 2*HWP + off)     = make_float4(o2[0],o2[1],o2[2],o2[3]);
    *(float4*)(out + 2*HWP + off + 4) = make_float4(o2[4],o2[5],o2[6],o2[7]);
  }
}

extern "C" void kernel_launch(void* const* d_in, const int* in_sizes, int n_in,
                              void* d_out, int out_size, void* d_ws, size_t ws_size,
                              hipStream_t stream) {
  const float* in = (const float*)d_in[0];
  float* out = (float*)d_out;
  dim3 grid((HH/8) * (WW/512));   // 1024 workgroups = exactly 4 per CU
  dim3 block(192);                // 3 waves: one per channel, 64 blocks each
  jpeg_kernel<<<grid, block, 0, stream>>>(in, out);
}